// Round 10
// baseline (707.986 us; speedup 1.0000x reference)
//
#include <hip/hip_runtime.h>
#include <cstdint>
#include <cstddef>

#define NN   10000
#define EE   40000
#define DIN_ 11
#define DD   64
#define LL   4
#define BB   512
#define MM   3
#define K1   128   // 2*D
#define DD2  4096  // D*D
#define NPB  16    // nodes per k_conv block
#define NCH  8     // total K-chunks (8 bf16-pairs each)
#define CSPL 2     // chunk-split across blocks
#define CPB  4     // chunks per block = NCH / CSPL
#define ESLOT 12   // register-accumulated edge slots per wave
#define ECREG (8 * ESLOT)  // 96 register-tracked edges per block

typedef unsigned short ushort_t;
typedef unsigned int   uint_t;

typedef __bf16 bf16x8_t __attribute__((ext_vector_type(8)));
typedef float  f32x4_t  __attribute__((ext_vector_type(4)));
union FragU { uint4 u; bf16x8_t b; };

__device__ __forceinline__ float bfu(ushort_t u) { return __uint_as_float(((uint_t)u) << 16); }
__device__ __forceinline__ float bflo(uint_t u) { return __uint_as_float(u << 16); }
__device__ __forceinline__ float bfhi(uint_t u) { return __uint_as_float(u & 0xffff0000u); }
__device__ __forceinline__ ushort_t f2bf(float f) {
  uint_t u = __float_as_uint(f);
  u = (u + 0x7fffu + ((u >> 16) & 1u)) >> 16;
  return (ushort_t)u;
}
__device__ __forceinline__ uint_t pack2(float lo, float hi) {
  return (uint_t)f2bf(lo) | ((uint_t)f2bf(hi) << 16);
}
__device__ __forceinline__ float sigmf_(float x) { return 1.f / (1.f + expf(-x)); }
__device__ __forceinline__ float siluf_(float x) { return x / (1.f + expf(-x)); }

#if defined(__HIP_DEVICE_COMPILE__) && __has_builtin(__builtin_amdgcn_fdot2_f32_bf16)
typedef __bf16 bf16x2_t __attribute__((ext_vector_type(2)));
__device__ __forceinline__ float dot2a(uint_t a, uint_t b, float c) {
  union { uint_t u; bf16x2_t v; } ua, ub;
  ua.u = a; ub.u = b;
  return __builtin_amdgcn_fdot2_f32_bf16(ua.v, ub.v, c, false);
}
#else
__device__ __forceinline__ float dot2a(uint_t a, uint_t b, float c) {
  return c + bflo(a) * bflo(b) + bfhi(a) * bfhi(b);
}
#endif

// ---------------- dtype detect: edge_attr is uniform[0,1) ----------------
__global__ void k_detect(const ushort_t* __restrict__ ea, int* __restrict__ flag) {
  __shared__ int bad;
  if (threadIdx.x == 0) bad = 0;
  __syncthreads();
  ushort_t u = ea[threadIdx.x];
  if ((u & 0x8000u) || u > 0x3F80u) atomicAdd(&bad, 1);
  __syncthreads();
  if (threadIdx.x == 0) *flag = (bad == 0) ? 1 : 0;
}

// ---------------- canonicalize float inputs to fp32 in ws ----------------
#define NCANON 16
struct CanonArgs {
  const void* src[NCANON];
  float* dst[NCANON];
  int n[NCANON];
};
__global__ void k_canon(CanonArgs a, const int* __restrict__ flag) {
  const int ai = blockIdx.y;
  const int n = a.n[ai];
  const int i = blockIdx.x * 256 + threadIdx.x;
  if (i >= n) return;
  float v;
  if (*flag) v = bfu(((const ushort_t*)a.src[ai])[i]);
  else       v = ((const float*)a.src[ai])[i];
  a.dst[ai][i] = v;
}

// ---------------- Wn2 repack into MFMA B-fragment order (coalesced) ----------------
// out uint index: ((((kpg*4+fc)*2+par)*2+hf)*64 + lane)*4 + jp
//   element = Wn2[2*kpg+par][(hf*32 + (lane>>4)*8 + 2*jp (+1))*64 + fc*16 + (lane&15)]
__global__ void k_wn2m(const void* __restrict__ Wn2, uint_t* __restrict__ out,
                       const int* __restrict__ flag) {
  __shared__ ushort_t row[DD2];  // 8 KB
  const int k = blockIdx.x, tid = threadIdx.x;
  if (*flag) {
    const uint4* src = (const uint4*)((const ushort_t*)Wn2 + (size_t)k * DD2);
    ((uint4*)row)[tid] = src[tid];
    ((uint4*)row)[tid + 256] = src[tid + 256];
  } else {
    const float* src = (const float*)Wn2 + (size_t)k * DD2;
    for (int j = 0; j < 16; ++j) row[tid + 256 * j] = f2bf(src[tid + 256 * j]);
  }
  __syncthreads();
  const int kpg = k >> 1, par = k & 1;
  const int lane = tid >> 2, jp = tid & 3;
  const int q = lane >> 4, n = lane & 15;
  for (int fc = 0; fc < 4; ++fc) {
#pragma unroll
    for (int hf = 0; hf < 2; ++hf) {
      int d0 = hf * 32 + q * 8 + 2 * jp;
      int f = fc * 16 + n;
      uint_t lo = row[d0 * 64 + f], hi = row[(d0 + 1) * 64 + f];
      out[((((size_t)kpg * 4 + fc) * 2 + par) * 2 + hf) * 256 + tid] = lo | (hi << 16);
    }
  }
}

// ---------------- LSTM weight transpose: Wiht[i][j], Whht[i][j] ----------------
__global__ void k_wT(const float* __restrict__ Wihc, const float* __restrict__ Whhc,
                     float* __restrict__ Wiht, float* __restrict__ Whht) {
  int idx = blockIdx.x * 256 + threadIdx.x;
  if (idx < 4 * DD * K1) {
    int j = idx >> 7, i = idx & 127;  // Wihc[j][i]
    Wiht[i * 256 + j] = Wihc[idx];
  }
  if (idx < 4 * DD * DD) {
    int j = idx >> 6, i = idx & 63;   // Whhc[j][i]
    Whht[i * 256 + j] = Whhc[idx];
  }
}

// ---------------- node embed: h, hpk, nbias ----------------
__global__ void k_embed(const float* __restrict__ x, const float* __restrict__ W0,
                        const float* __restrict__ b0, const float* __restrict__ bn2,
                        float* __restrict__ h, uint_t* __restrict__ hpk,
                        float* __restrict__ nbias) {
  __shared__ float xs[DIN_];
  __shared__ float hl[DD];
  const int n = blockIdx.x, f = threadIdx.x;
  if (f < DIN_) xs[f] = x[n * DIN_ + f];
  __syncthreads();
  float a = b0[f];
  for (int i = 0; i < DIN_; ++i) a += xs[i] * W0[i * DD + f];
  h[(size_t)n * DD + f] = a;
  hl[f] = a;
  float other = __shfl_down(a, 1);
  if ((f & 1) == 0)
    hpk[(size_t)n * 32 + (f >> 1)] = pack2(a, other);
  __syncthreads();
  float nb = 0.f;
#pragma unroll
  for (int d = 0; d < DD; ++d) nb += hl[d] * bn2[d * DD + f];
  nbias[(size_t)n * DD + f] = nb;
}

// ---------------- edge MLP layer1 -> hn1c, chunk-major CSR order ----------------
// hn1c[((j>>3)*EE + pos)*8 + (j&7)] : chunk c holds pairs c*8..c*8+7 of each edge.
__global__ void k_edgemlp(const float* __restrict__ ea, const float* __restrict__ Wn1,
                          const float* __restrict__ bn1, const int* __restrict__ epos,
                          uint_t* __restrict__ hn1c) {
  int idx = blockIdx.x * 256 + threadIdx.x;  // e*64 + j
  if (idx >= EE * (K1 / 2)) return;
  int e = idx >> 6, j = idx & 63;
  int k0 = 2 * j, k1 = 2 * j + 1;
  float a0 = ea[e * 4 + 0], a1 = ea[e * 4 + 1], a2 = ea[e * 4 + 2], a3 = ea[e * 4 + 3];
  float t0 = bn1[k0] + a0 * Wn1[k0] + a1 * Wn1[K1 + k0] + a2 * Wn1[2 * K1 + k0] + a3 * Wn1[3 * K1 + k0];
  float t1 = bn1[k1] + a0 * Wn1[k1] + a1 * Wn1[K1 + k1] + a2 * Wn1[2 * K1 + k1] + a3 * Wn1[3 * K1 + k1];
  int pos = epos[e];
  hn1c[((size_t)(j >> 3) * EE + pos) * 8 + (j & 7)] = pack2(siluf_(t0), siluf_(t1));
}

// ---------------- src-CSR build ----------------
__global__ void k_hist(const int* __restrict__ ei, int* __restrict__ cnt_s) {
  int e = blockIdx.x * 256 + threadIdx.x;
  if (e >= EE) return;
  atomicAdd(&cnt_s[ei[e]], 1);
}

__global__ void k_scan(const int* __restrict__ cnt, int* __restrict__ rp) {
  __shared__ int part[1024];
  const int tid = threadIdx.x;
  const int chunk = (NN + 1023) / 1024;
  int s = 0;
  for (int j = 0; j < chunk; ++j) {
    int idx = tid * chunk + j;
    if (idx < NN) s += cnt[idx];
  }
  part[tid] = s;
  __syncthreads();
  for (int off = 1; off < 1024; off <<= 1) {
    int v = (tid >= off) ? part[tid - off] : 0;
    __syncthreads();
    part[tid] += v;
    __syncthreads();
  }
  int base = (tid == 0) ? 0 : part[tid - 1];
  for (int j = 0; j < chunk; ++j) {
    int idx = tid * chunk + j;
    if (idx < NN) { rp[idx] = base; base += cnt[idx]; }
  }
  if (tid == 1023) rp[NN] = part[1023];
}

// epos[e] = CSR slot of edge e; esd[2*pos..] = (src, dst)
__global__ void k_fill(const int* __restrict__ ei, const int* __restrict__ rps,
                       int* __restrict__ cur_s, int* __restrict__ epos,
                       int* __restrict__ esd) {
  int e = blockIdx.x * 256 + threadIdx.x;
  if (e >= EE) return;
  int s = ei[e], d = ei[EE + e];
  int ps = atomicAdd(&cur_s[s], 1);
  int pos = rps[s] + ps;
  epos[e] = pos;
  esd[2 * pos] = s;
  esd[2 * pos + 1] = d;
}

// graph segment offsets from sorted batch
__global__ void k_goff(const int* __restrict__ batch, int* __restrict__ goff) {
  int g = blockIdx.x * 256 + threadIdx.x;
  if (g > BB) return;
  int lo = 0, hi = NN;
  while (lo < hi) {
    int mid = (lo + hi) >> 1;
    if (batch[mid] < g) lo = mid + 1; else hi = mid;
  }
  goff[g] = lo;
}

// ---------------- fused NNConv message kernel ----------------
// Grid: CSPL*625, 512 threads. half = bx/625 (K halves), ng = bx%625 (node group).
// Block serializes CPB=4 chunks of 8 kp. Per chunk: wave w computes kp w via MFMA
// into 32 KB LDS; then each wave updates its register-resident edge partials
// (acc[ESLOT], edges strided by 8). ONE atomicAdd per edge per half at the end.
__global__ __launch_bounds__(512, 8) void k_conv(
    const uint_t* __restrict__ hpk, const uint_t* __restrict__ hn1c,
    const uint_t* __restrict__ Wn2m, const float* __restrict__ nbias,
    const int* __restrict__ rps, const int* __restrict__ esd,
    float* __restrict__ aggr) {
  __shared__ uint_t Gp[NPB * 2 * 64 * 4];  // 32 KB: ((m*2+kq)*64+f)*4 + slot
  __shared__ int2 eStage[ECREG];           // 768 B
  const int tid = threadIdx.x;
  const int w = tid >> 6, lane = tid & 63;
  const int q = lane >> 4, n16 = lane & 15;
  const int half = blockIdx.x / 625;
  const int ng = blockIdx.x - half * 625;
  const int n0 = ng * NPB;
  const int e0 = rps[n0], e1 = rps[n0 + NPB];
  const int ecnt = e1 - e0;

  if (tid < ECREG && tid < ecnt) eStage[tid] = ((const int2*)esd)[e0 + tid];

  FragU a0, a1;
  {
    const uint4* ap = (const uint4*)(hpk + (size_t)(n0 + n16) * 32);
    a0.u = ap[q];
    a1.u = ap[4 + q];
  }
  __syncthreads();  // eStage visible

  // seed register accumulators (nbias on half 0)
  float acc[ESLOT];
#pragma unroll
  for (int s = 0; s < ESLOT; ++s) {
    const int li = w + 8 * s;
    float v = 0.f;
    if (half == 0 && li < ecnt && li < ECREG)
      v = nbias[(size_t)eStage[li].x * 64 + lane];
    acc[s] = v;
  }

  const int kq = w >> 2, slot = w & 3;
  for (int cc = 0; cc < CPB; ++cc) {
    const int c = half * CPB + cc;
    if (cc) __syncthreads();  // prior phase-2 reads done
    // ---- phase 1: wave w computes chunk-local kp = w ----
    const int kpg = c * 8 + w;
    for (int fc = 0; fc < 4; ++fc) {
      const uint4* bp = (const uint4*)Wn2m + (size_t)(kpg * 4 + fc) * 256 + lane;
      FragU b00, b01, b10, b11;
      b00.u = bp[0];    // par0 hf0
      b01.u = bp[64];   // par0 hf1
      b10.u = bp[128];  // par1 hf0
      b11.u = bp[192];  // par1 hf1
      f32x4_t acc0 = {0.f, 0.f, 0.f, 0.f};
      f32x4_t acc1 = {0.f, 0.f, 0.f, 0.f};
      acc0 = __builtin_amdgcn_mfma_f32_16x16x32_bf16(a0.b, b00.b, acc0, 0, 0, 0);
      acc0 = __builtin_amdgcn_mfma_f32_16x16x32_bf16(a1.b, b01.b, acc0, 0, 0, 0);
      acc1 = __builtin_amdgcn_mfma_f32_16x16x32_bf16(a0.b, b10.b, acc1, 0, 0, 0);
      acc1 = __builtin_amdgcn_mfma_f32_16x16x32_bf16(a1.b, b11.b, acc1, 0, 0, 0);
#pragma unroll
      for (int r = 0; r < 4; ++r) {
        const int m = q * 4 + r;  // D row = node index
        Gp[(((m * 2 + kq) * 64 + fc * 16 + n16) * 4 + slot)] = pack2(acc0[r], acc1[r]);
      }
    }
    __syncthreads();
    // ---- phase 2: register-resident edge partials ----
#pragma unroll
    for (int s = 0; s < ESLOT; ++s) {
      const int li = w + 8 * s;
      if (li < ecnt && li < ECREG) {
        const int2 sd = eStage[li];
        const int m = sd.x - n0;
        const uint4* hp = (const uint4*)(hn1c + ((size_t)c * EE + e0 + li) * 8);
        uint4 hv0 = hp[0], hv1 = hp[1];
        const uint4* gb = (const uint4*)Gp + (size_t)(m * 2) * 64 + lane;
        uint4 g0 = gb[0], g1 = gb[64];
        float p = acc[s];
        p = dot2a(g0.x, hv0.x, p);
        p = dot2a(g0.y, hv0.y, p);
        p = dot2a(g0.z, hv0.z, p);
        p = dot2a(g0.w, hv0.w, p);
        p = dot2a(g1.x, hv1.x, p);
        p = dot2a(g1.y, hv1.y, p);
        p = dot2a(g1.z, hv1.z, p);
        p = dot2a(g1.w, hv1.w, p);
        acc[s] = p;
      }
    }
    // overflow edges (virtually never): per-chunk atomic path
    for (int li = ECREG + w; li < ecnt; li += 8) {
      const int ii = e0 + li;
      const int src = __builtin_amdgcn_readfirstlane(esd[2 * ii]);
      const int dst = __builtin_amdgcn_readfirstlane(esd[2 * ii + 1]);
      const int m = src - n0;
      float p = (half == 0 && cc == 0) ? nbias[(size_t)src * 64 + lane] : 0.f;
      const uint4* hp = (const uint4*)(hn1c + ((size_t)c * EE + ii) * 8);
      uint4 hv0 = hp[0], hv1 = hp[1];
      const uint4* gb = (const uint4*)Gp + (size_t)(m * 2) * 64 + lane;
      uint4 g0 = gb[0], g1 = gb[64];
      p = dot2a(g0.x, hv0.x, p);
      p = dot2a(g0.y, hv0.y, p);
      p = dot2a(g0.z, hv0.z, p);
      p = dot2a(g0.w, hv0.w, p);
      p = dot2a(g1.x, hv1.x, p);
      p = dot2a(g1.y, hv1.y, p);
      p = dot2a(g1.z, hv1.z, p);
      p = dot2a(g1.w, hv1.w, p);
      atomicAdd(&aggr[(size_t)dst * 64 + lane], p);
    }
  }
  // ---- commit: one atomic per register-tracked edge ----
#pragma unroll
  for (int s = 0; s < ESLOT; ++s) {
    const int li = w + 8 * s;
    if (li < ecnt && li < ECREG) {
      const int dst = eStage[li].y;
      atomicAdd(&aggr[(size_t)dst * 64 + lane], acc[s]);
    }
  }
}

// ---------------- h update: 4 nodes/block; residual + aggr + root GEMM; re-zeros aggr ----------------
__global__ __launch_bounds__(256) void k_update(
    float* __restrict__ h, uint_t* __restrict__ hpk,
    float* __restrict__ aggr, const float* __restrict__ bn2,
    const float* __restrict__ root, const float* __restrict__ cb,
    float* __restrict__ nbias, int l) {
  __shared__ float hl[4][DD];
  __shared__ float al[4][DD];
  const int tid = threadIdx.x, w = tid >> 6, f = tid & 63;
  const int n = blockIdx.x * 4 + w;
  float hv = h[(size_t)n * DD + f];
  hl[w][f] = hv;
  float acc = hv + aggr[(size_t)n * DD + f] + cb[l * DD + f];
  aggr[(size_t)n * DD + f] = 0.f;
  __syncthreads();
  const float* rp = root + (size_t)l * DD2;
#pragma unroll
  for (int d = 0; d < DD; ++d) acc += hl[w][d] * rp[d * DD + f];
  h[(size_t)n * DD + f] = acc;
  al[w][f] = acc;
  float other = __shfl_down(acc, 1);
  if ((f & 1) == 0)
    hpk[(size_t)n * 32 + (f >> 1)] = pack2(acc, other);
  __syncthreads();
  float nb = 0.f;
#pragma unroll
  for (int d = 0; d < DD; ++d) nb += al[w][d] * bn2[d * DD + f];
  nbias[(size_t)n * DD + f] = nb;
}

// ---------------- fused Set2Set (3x LSTM+attention) + output MLP ----------------
#define EVCAP 2048
__global__ void k_s2s(const float* __restrict__ h, const int* __restrict__ goff,
                      const float* __restrict__ Wiht, const float* __restrict__ Whht,
                      const float* __restrict__ lb,
                      const float* __restrict__ Wo1, const float* __restrict__ bo1,
                      const float* __restrict__ Wo2, const float* __restrict__ bo2,
                      void* __restrict__ outv, const int* __restrict__ flag) {
  __shared__ float qsl[K1];
  __shared__ float hsl[DD];
  __shared__ float csl[DD];
  __shared__ float gl[4][DD];
  __shared__ float red[256];
  __shared__ float ev[EVCAP];
  __shared__ float rp4[4][DD];
  const int g = blockIdx.x, tid = threadIdx.x;

  if (tid < K1) qsl[tid] = 0.f;
  else if (tid < K1 + DD) hsl[tid - K1] = 0.f;
  else csl[tid - K1 - DD] = 0.f;
  __syncthreads();

  const int i0 = goff[g];
  int cnt = goff[g + 1] - i0;
  if (cnt > EVCAP) cnt = EVCAP;

  for (int m = 0; m < MM; ++m) {
    {
      float a = lb[tid];
      for (int i = 0; i < K1; ++i) a += qsl[i] * Wiht[i * 256 + tid];
      for (int i = 0; i < DD; ++i) a += hsl[i] * Whht[i * 256 + tid];
      gl[tid >> 6][tid & 63] = a;
    }
    __syncthreads();
    if (tid < DD) {
      float ig = sigmf_(gl[0][tid]), fg = sigmf_(gl[1][tid]);
      float gg = tanhf(gl[2][tid]), og = sigmf_(gl[3][tid]);
      float c = fg * csl[tid] + ig * gg;
      csl[tid] = c;
      hsl[tid] = og * tanhf(c);
    }
    __syncthreads();
    float lmax = -1e30f;
    for (int jj = tid; jj < cnt; jj += 256) {
      const float* hp = h + (size_t)(i0 + jj) * DD;
      float e = 0.f;
#pragma unroll
      for (int d = 0; d < DD; ++d) e += hp[d] * hsl[d];
      ev[jj] = e;
      lmax = fmaxf(lmax, e);
    }
    red[tid] = lmax;
    __syncthreads();
    for (int s = 128; s > 0; s >>= 1) {
      if (tid < s) red[tid] = fmaxf(red[tid], red[tid + s]);
      __syncthreads();
    }
    const float emax = red[0];
    __syncthreads();
    float lsum = 0.f;
    for (int jj = tid; jj < cnt; jj += 256) {
      float ex = expf(ev[jj] - emax);
      ev[jj] = ex;
      lsum += ex;
    }
    red[tid] = lsum;
    __syncthreads();
    for (int s = 128; s > 0; s >>= 1) {
      if (tid < s) red[tid] += red[tid + s];
      __syncthreads();
    }
    const float denom = red[0];
    const int f = tid & 63, grp = tid >> 6;
    float acc = 0.f;
    for (int jj = grp; jj < cnt; jj += 4)
      acc += ev[jj] * h[(size_t)(i0 + jj) * DD + f];
    rp4[grp][f] = acc;
    __syncthreads();
    if (tid < DD) {
      float r = rp4[0][tid] + rp4[1][tid] + rp4[2][tid] + rp4[3][tid];
      r = (cnt > 0 && denom > 0.f) ? r / denom : 0.f;
      qsl[tid] = hsl[tid];
      qsl[DD + tid] = r;
    }
    __syncthreads();
  }
  if (tid < DD) {
    float t = bo1[tid];
    for (int i = 0; i < K1; ++i) t += qsl[i] * Wo1[i * DD + tid];
    float s = siluf_(t) * Wo2[tid];
    for (int off = 32; off > 0; off >>= 1) s += __shfl_down(s, off);
    if (tid == 0) {
      float v = s + bo2[0];
      if (*flag) ((ushort_t*)outv)[g] = f2bf(v);
      else       ((float*)outv)[g] = v;
    }
  }
}

extern "C" void kernel_launch(void* const* d_in, const int* in_sizes, int n_in,
                              void* d_out, int out_size, void* d_ws, size_t ws_size,
                              hipStream_t stream) {
  const void* x_r    = d_in[0];
  const int*  ei     = (const int*)d_in[1];
  const void* ea_r   = d_in[2];
  const int*  batch  = (const int*)d_in[3];
  const void* W0_r   = d_in[4];
  const void* b0_r   = d_in[5];
  const void* Wn1_r  = d_in[6];
  const void* bn1_r  = d_in[7];
  const void* Wn2_r  = d_in[8];
  const void* bn2_r  = d_in[9];
  const void* root_r = d_in[10];
  const void* cb_r   = d_in[11];
  const void* Wih_r  = d_in[12];
  const void* Whh_r  = d_in[13];
  const void* lb_r   = d_in[14];
  const void* Wo1_r  = d_in[15];
  const void* bo1_r  = d_in[16];
  const void* Wo2_r  = d_in[17];
  const void* bo2_r  = d_in[18];

  char* w = (char*)d_ws;
  size_t off = 0;
  auto alloc = [&](size_t bytes) -> void* {
    void* p = w + off;
    off = (off + bytes + 255) & ~(size_t)255;
    return p;
  };
  int* flag = (int*)alloc(4);
  float* xc    = (float*)alloc((size_t)NN * DIN_ * 4);
  float* eac   = (float*)alloc((size_t)EE * 4 * 4);
  float* W0c   = (float*)alloc((size_t)DIN_ * DD * 4);
  float* b0c   = (float*)alloc((size_t)DD * 4);
  float* Wn1c  = (float*)alloc((size_t)4 * K1 * 4);
  float* bn1c  = (float*)alloc((size_t)K1 * 4);
  float* bn2c  = (float*)alloc((size_t)DD2 * 4);
  float* rootc = (float*)alloc((size_t)LL * DD2 * 4);
  float* cbc   = (float*)alloc((size_t)LL * DD * 4);
  float* Wihc  = (float*)alloc((size_t)4 * DD * K1 * 4);
  float* Whhc  = (float*)alloc((size_t)4 * DD * DD * 4);
  float* lbc   = (float*)alloc((size_t)4 * DD * 4);
  float* Wo1c  = (float*)alloc((size_t)K1 * DD * 4);
  float* bo1c  = (float*)alloc((size_t)DD * 4);
  float* Wo2c  = (float*)alloc((size_t)DD * 4);
  float* bo2c  = (float*)alloc((size_t)4);
  float* Wiht  = (float*)alloc((size_t)K1 * 256 * 4);
  float* Whht  = (float*)alloc((size_t)DD * 256 * 4);
  uint_t* Wn2m = (uint_t*)alloc((size_t)64 * 4 * 2 * 2 * 64 * 4 * 4);  // 1 MB
  float*  h    = (float*)alloc((size_t)NN * DD * 4);
  uint_t* hpk  = (uint_t*)alloc((size_t)NN * 32 * 4);
  uint_t* hn1c = (uint_t*)alloc((size_t)EE * (K1 / 2) * 4);  // chunk-major
  float*  aggr = (float*)alloc((size_t)NN * DD * 4);
  float*  nbias= (float*)alloc((size_t)NN * DD * 4);
  int* cnts  = (int*)alloc((size_t)2 * NN * 4);
  int* rps   = (int*)alloc((size_t)(NN + 1) * 4);
  int* epos  = (int*)alloc((size_t)EE * 4);
  int* esd   = (int*)alloc((size_t)2 * EE * 4);
  int* goff  = (int*)alloc((size_t)(BB + 1) * 4);

  int* cnt_s = cnts;
  int* cur_s = cnts + NN;

  hipMemsetAsync(cnts, 0, (size_t)2 * NN * 4, stream);
  hipMemsetAsync(aggr, 0, (size_t)NN * DD * 4, stream);

  k_detect<<<1, 256, 0, stream>>>((const ushort_t*)ea_r, flag);

  CanonArgs ca;
  const void* srcs[NCANON] = {x_r, ea_r, W0_r, b0_r, Wn1_r, bn1_r, bn2_r, root_r,
                              cb_r, Wih_r, Whh_r, lb_r, Wo1_r, bo1_r, Wo2_r, bo2_r};
  float* dsts[NCANON] = {xc, eac, W0c, b0c, Wn1c, bn1c, bn2c, rootc,
                         cbc, Wihc, Whhc, lbc, Wo1c, bo1c, Wo2c, bo2c};
  int cnts_c[NCANON] = {NN * DIN_, EE * 4, DIN_ * DD, DD, 4 * K1, K1, DD2, LL * DD2,
                        LL * DD, 4 * DD * K1, 4 * DD * DD, 4 * DD, K1 * DD, DD, DD, 1};
  for (int i = 0; i < NCANON; ++i) { ca.src[i] = srcs[i]; ca.dst[i] = dsts[i]; ca.n[i] = cnts_c[i]; }
  {
    dim3 grid((EE * 4 + 255) / 256, NCANON);
    k_canon<<<grid, 256, 0, stream>>>(ca, flag);
  }
  k_wn2m<<<K1, 256, 0, stream>>>(Wn2_r, Wn2m, flag);
  k_wT<<<(4 * DD * K1 + 255) / 256, 256, 0, stream>>>(Wihc, Whhc, Wiht, Whht);

  k_embed<<<NN, DD, 0, stream>>>(xc, W0c, b0c, bn2c, h, hpk, nbias);
  k_hist<<<(EE + 255) / 256, 256, 0, stream>>>(ei, cnt_s);
  k_scan<<<1, 1024, 0, stream>>>(cnt_s, rps);
  k_fill<<<(EE + 255) / 256, 256, 0, stream>>>(ei, rps, cur_s, epos, esd);
  k_goff<<<(BB + 1 + 255) / 256, 256, 0, stream>>>(batch, goff);
  k_edgemlp<<<(EE * (K1 / 2) + 255) / 256, 256, 0, stream>>>(eac, Wn1c, bn1c, epos, hn1c);

  for (int l = 0; l < LL; ++l) {
    k_conv<<<CSPL * (NN / NPB), 512, 0, stream>>>(hpk, hn1c, Wn2m, nbias, rps, esd, aggr);
    k_update<<<NN / 4, 256, 0, stream>>>(h, hpk, aggr, bn2c, rootc, cbc, nbias, l);
  }

  k_s2s<<<BB, 256, 0, stream>>>(h, goff, Wiht, Whht, lbc, Wo1c, bo1c, Wo2c, bo2c,
                                d_out, flag);
}

// Round 11
// 460.703 us; speedup vs baseline: 1.5368x; 1.5368x over previous
//
#include <hip/hip_runtime.h>
#include <cstdint>
#include <cstddef>

#define NN   10000
#define EE   40000
#define DIN_ 11
#define DD   64
#define LL   4
#define BB   512
#define MM   3
#define K1   128   // 2*D
#define DD2  4096  // D*D
#define NPB  16    // nodes per k_conv block
#define NCH  8     // total K-chunks (8 bf16-pairs each)
#define CSPL 2     // chunk-split across blocks
#define CPB  4     // chunks per block = NCH / CSPL
#define ESLOT 12   // register-accumulated edge slots per wave
#define ECREG (8 * ESLOT)  // 96 register-tracked edges per block

typedef unsigned short ushort_t;
typedef unsigned int   uint_t;

typedef __bf16 bf16x8_t __attribute__((ext_vector_type(8)));
typedef float  f32x4_t  __attribute__((ext_vector_type(4)));
union FragU { uint4 u; bf16x8_t b; };

__device__ __forceinline__ float bfu(ushort_t u) { return __uint_as_float(((uint_t)u) << 16); }
__device__ __forceinline__ float bflo(uint_t u) { return __uint_as_float(u << 16); }
__device__ __forceinline__ float bfhi(uint_t u) { return __uint_as_float(u & 0xffff0000u); }
__device__ __forceinline__ ushort_t f2bf(float f) {
  uint_t u = __float_as_uint(f);
  u = (u + 0x7fffu + ((u >> 16) & 1u)) >> 16;
  return (ushort_t)u;
}
__device__ __forceinline__ uint_t pack2(float lo, float hi) {
  return (uint_t)f2bf(lo) | ((uint_t)f2bf(hi) << 16);
}
__device__ __forceinline__ float sigmf_(float x) { return 1.f / (1.f + expf(-x)); }
__device__ __forceinline__ float siluf_(float x) { return x / (1.f + expf(-x)); }

#if defined(__HIP_DEVICE_COMPILE__) && __has_builtin(__builtin_amdgcn_fdot2_f32_bf16)
typedef __bf16 bf16x2_t __attribute__((ext_vector_type(2)));
__device__ __forceinline__ float dot2a(uint_t a, uint_t b, float c) {
  union { uint_t u; bf16x2_t v; } ua, ub;
  ua.u = a; ub.u = b;
  return __builtin_amdgcn_fdot2_f32_bf16(ua.v, ub.v, c, false);
}
#else
__device__ __forceinline__ float dot2a(uint_t a, uint_t b, float c) {
  return c + bflo(a) * bflo(b) + bfhi(a) * bfhi(b);
}
#endif

// ---------------- canonicalize float inputs to fp32 (self-detecting dtype) ----------------
// edge_attr is uniform[0,1): if bf16, every ushort has sign=0 and value <= 0x3F80.
// Each block re-derives the flag from the same 256 ushorts (deterministic); block (0,0)
// publishes it for later kernels.
#define NCANON 16
struct CanonArgs {
  const void* src[NCANON];
  float* dst[NCANON];
  int n[NCANON];
};
__global__ void k_canon(CanonArgs a, const ushort_t* __restrict__ ea, int* __restrict__ flag) {
  __shared__ int bad;
  if (threadIdx.x == 0) bad = 0;
  __syncthreads();
  ushort_t u = ea[threadIdx.x];
  if ((u & 0x8000u) || u > 0x3F80u) atomicAdd(&bad, 1);
  __syncthreads();
  const int isbf = (bad == 0) ? 1 : 0;
  if (blockIdx.x == 0 && blockIdx.y == 0 && threadIdx.x == 0) *flag = isbf;
  const int ai = blockIdx.y;
  const int n = a.n[ai];
  const int i = blockIdx.x * 256 + threadIdx.x;
  if (i >= n) return;
  float v;
  if (isbf) v = bfu(((const ushort_t*)a.src[ai])[i]);
  else      v = ((const float*)a.src[ai])[i];
  a.dst[ai][i] = v;
}

// ---------------- Wn2 repack into MFMA B-fragment order (coalesced) ----------------
// out uint index: ((((kpg*4+fc)*2+par)*2+hf)*64 + lane)*4 + jp
//   element = Wn2[2*kpg+par][(hf*32 + (lane>>4)*8 + 2*jp (+1))*64 + fc*16 + (lane&15)]
__global__ void k_wn2m(const void* __restrict__ Wn2, uint_t* __restrict__ out,
                       const int* __restrict__ flag) {
  __shared__ ushort_t row[DD2];  // 8 KB
  const int k = blockIdx.x, tid = threadIdx.x;
  if (*flag) {
    const uint4* src = (const uint4*)((const ushort_t*)Wn2 + (size_t)k * DD2);
    ((uint4*)row)[tid] = src[tid];
    ((uint4*)row)[tid + 256] = src[tid + 256];
  } else {
    const float* src = (const float*)Wn2 + (size_t)k * DD2;
    for (int j = 0; j < 16; ++j) row[tid + 256 * j] = f2bf(src[tid + 256 * j]);
  }
  __syncthreads();
  const int kpg = k >> 1, par = k & 1;
  const int lane = tid >> 2, jp = tid & 3;
  const int q = lane >> 4, n = lane & 15;
  for (int fc = 0; fc < 4; ++fc) {
#pragma unroll
    for (int hf = 0; hf < 2; ++hf) {
      int d0 = hf * 32 + q * 8 + 2 * jp;
      int f = fc * 16 + n;
      uint_t lo = row[d0 * 64 + f], hi = row[(d0 + 1) * 64 + f];
      out[((((size_t)kpg * 4 + fc) * 2 + par) * 2 + hf) * 256 + tid] = lo | (hi << 16);
    }
  }
}

// ---------------- LSTM weight transpose: Wiht[i][j], Whht[i][j] ----------------
__global__ void k_wT(const float* __restrict__ Wihc, const float* __restrict__ Whhc,
                     float* __restrict__ Wiht, float* __restrict__ Whht) {
  int idx = blockIdx.x * 256 + threadIdx.x;
  if (idx < 4 * DD * K1) {
    int j = idx >> 7, i = idx & 127;  // Wihc[j][i]
    Wiht[i * 256 + j] = Wihc[idx];
  }
  if (idx < 4 * DD * DD) {
    int j = idx >> 6, i = idx & 63;   // Whhc[j][i]
    Whht[i * 256 + j] = Whhc[idx];
  }
}

// ---------------- node embed: h, hpk, nbias ----------------
__global__ void k_embed(const float* __restrict__ x, const float* __restrict__ W0,
                        const float* __restrict__ b0, const float* __restrict__ bn2,
                        float* __restrict__ h, uint_t* __restrict__ hpk,
                        float* __restrict__ nbias) {
  __shared__ float xs[DIN_];
  __shared__ float hl[DD];
  const int n = blockIdx.x, f = threadIdx.x;
  if (f < DIN_) xs[f] = x[n * DIN_ + f];
  __syncthreads();
  float a = b0[f];
  for (int i = 0; i < DIN_; ++i) a += xs[i] * W0[i * DD + f];
  h[(size_t)n * DD + f] = a;
  hl[f] = a;
  float other = __shfl_down(a, 1);
  if ((f & 1) == 0)
    hpk[(size_t)n * 32 + (f >> 1)] = pack2(a, other);
  __syncthreads();
  float nb = 0.f;
#pragma unroll
  for (int d = 0; d < DD; ++d) nb += hl[d] * bn2[d * DD + f];
  nbias[(size_t)n * DD + f] = nb;
}

// ---------------- edge MLP layer1 -> hn1c, chunk-major CSR order ----------------
// hn1c[((j>>3)*EE + pos)*8 + (j&7)] : chunk c holds pairs c*8..c*8+7 of each edge.
__global__ void k_edgemlp(const float* __restrict__ ea, const float* __restrict__ Wn1,
                          const float* __restrict__ bn1, const int* __restrict__ epos,
                          uint_t* __restrict__ hn1c) {
  int idx = blockIdx.x * 256 + threadIdx.x;  // e*64 + j
  if (idx >= EE * (K1 / 2)) return;
  int e = idx >> 6, j = idx & 63;
  int k0 = 2 * j, k1 = 2 * j + 1;
  float a0 = ea[e * 4 + 0], a1 = ea[e * 4 + 1], a2 = ea[e * 4 + 2], a3 = ea[e * 4 + 3];
  float t0 = bn1[k0] + a0 * Wn1[k0] + a1 * Wn1[K1 + k0] + a2 * Wn1[2 * K1 + k0] + a3 * Wn1[3 * K1 + k0];
  float t1 = bn1[k1] + a0 * Wn1[k1] + a1 * Wn1[K1 + k1] + a2 * Wn1[2 * K1 + k1] + a3 * Wn1[3 * K1 + k1];
  int pos = epos[e];
  hn1c[((size_t)(j >> 3) * EE + pos) * 8 + (j & 7)] = pack2(siluf_(t0), siluf_(t1));
}

// ---------------- src-CSR build ----------------
__global__ void k_hist(const int* __restrict__ ei, int* __restrict__ cnt_s) {
  int e = blockIdx.x * 256 + threadIdx.x;
  if (e >= EE) return;
  atomicAdd(&cnt_s[ei[e]], 1);
}

// block 0: exclusive scan of cnt -> rp; block 1: goff from sorted batch
__global__ void k_scan(const int* __restrict__ cnt, int* __restrict__ rp,
                       const int* __restrict__ batch, int* __restrict__ goff) {
  if (blockIdx.x == 1) {
    int g = threadIdx.x;
    if (g > BB) return;
    int lo = 0, hi = NN;
    while (lo < hi) {
      int mid = (lo + hi) >> 1;
      if (batch[mid] < g) lo = mid + 1; else hi = mid;
    }
    goff[g] = lo;
    return;
  }
  __shared__ int part[1024];
  const int tid = threadIdx.x;
  const int chunk = (NN + 1023) / 1024;
  int s = 0;
  for (int j = 0; j < chunk; ++j) {
    int idx = tid * chunk + j;
    if (idx < NN) s += cnt[idx];
  }
  part[tid] = s;
  __syncthreads();
  for (int off = 1; off < 1024; off <<= 1) {
    int v = (tid >= off) ? part[tid - off] : 0;
    __syncthreads();
    part[tid] += v;
    __syncthreads();
  }
  int base = (tid == 0) ? 0 : part[tid - 1];
  for (int j = 0; j < chunk; ++j) {
    int idx = tid * chunk + j;
    if (idx < NN) { rp[idx] = base; base += cnt[idx]; }
  }
  if (tid == 1023) rp[NN] = part[1023];
}

// epos[e] = CSR slot of edge e; esd[2*pos..] = (src, dst)
__global__ void k_fill(const int* __restrict__ ei, const int* __restrict__ rps,
                       int* __restrict__ cur_s, int* __restrict__ epos,
                       int* __restrict__ esd) {
  int e = blockIdx.x * 256 + threadIdx.x;
  if (e >= EE) return;
  int s = ei[e], d = ei[EE + e];
  int ps = atomicAdd(&cur_s[s], 1);
  int pos = rps[s] + ps;
  epos[e] = pos;
  esd[2 * pos] = s;
  esd[2 * pos + 1] = d;
}

// ---------------- fused NNConv message kernel ----------------
// Grid: CSPL*625, 512 threads. half = bx/625 (K halves), ng = bx%625 (node group).
// Block serializes CPB=4 chunks of 8 kp. Per chunk: wave w computes kp w via MFMA
// into 32 KB LDS; then each wave updates its register-resident edge partials
// (acc[ESLOT], edges strided by 8). ONE atomicAdd per edge per half at the end.
// launch_bounds (512,4): 128-VGPR budget so acc[] stays in registers (R10's (512,8)
// forced a 64-VGPR cap -> scratch spills -> 300 MB/layer of spill traffic).
__global__ __launch_bounds__(512, 4) void k_conv(
    const uint_t* __restrict__ hpk, const uint_t* __restrict__ hn1c,
    const uint_t* __restrict__ Wn2m, const float* __restrict__ nbias,
    const int* __restrict__ rps, const int* __restrict__ esd,
    float* __restrict__ aggr) {
  __shared__ uint_t Gp[NPB * 2 * 64 * 4];  // 32 KB: ((m*2+kq)*64+f)*4 + slot
  __shared__ int2 eStage[ECREG];           // 768 B
  const int tid = threadIdx.x;
  const int w = tid >> 6, lane = tid & 63;
  const int q = lane >> 4, n16 = lane & 15;
  const int half = blockIdx.x / 625;
  const int ng = blockIdx.x - half * 625;
  const int n0 = ng * NPB;
  const int e0 = rps[n0], e1 = rps[n0 + NPB];
  const int ecnt = e1 - e0;

  if (tid < ECREG && tid < ecnt) eStage[tid] = ((const int2*)esd)[e0 + tid];

  FragU a0, a1;
  {
    const uint4* ap = (const uint4*)(hpk + (size_t)(n0 + n16) * 32);
    a0.u = ap[q];
    a1.u = ap[4 + q];
  }
  __syncthreads();  // eStage visible

  // seed register accumulators (nbias on half 0)
  float acc[ESLOT];
#pragma unroll
  for (int s = 0; s < ESLOT; ++s) {
    const int li = w + 8 * s;
    float v = 0.f;
    if (half == 0 && li < ecnt && li < ECREG)
      v = nbias[(size_t)eStage[li].x * 64 + lane];
    acc[s] = v;
  }

  const int kq = w >> 2, slot = w & 3;
  for (int cc = 0; cc < CPB; ++cc) {
    const int c = half * CPB + cc;
    if (cc) __syncthreads();  // prior phase-2 reads done
    // ---- phase 1: wave w computes chunk-local kp = w ----
    const int kpg = c * 8 + w;
    for (int fc = 0; fc < 4; ++fc) {
      const uint4* bp = (const uint4*)Wn2m + (size_t)(kpg * 4 + fc) * 256 + lane;
      FragU b00, b01, b10, b11;
      b00.u = bp[0];    // par0 hf0
      b01.u = bp[64];   // par0 hf1
      b10.u = bp[128];  // par1 hf0
      b11.u = bp[192];  // par1 hf1
      f32x4_t acc0 = {0.f, 0.f, 0.f, 0.f};
      f32x4_t acc1 = {0.f, 0.f, 0.f, 0.f};
      acc0 = __builtin_amdgcn_mfma_f32_16x16x32_bf16(a0.b, b00.b, acc0, 0, 0, 0);
      acc0 = __builtin_amdgcn_mfma_f32_16x16x32_bf16(a1.b, b01.b, acc0, 0, 0, 0);
      acc1 = __builtin_amdgcn_mfma_f32_16x16x32_bf16(a0.b, b10.b, acc1, 0, 0, 0);
      acc1 = __builtin_amdgcn_mfma_f32_16x16x32_bf16(a1.b, b11.b, acc1, 0, 0, 0);
#pragma unroll
      for (int r = 0; r < 4; ++r) {
        const int m = q * 4 + r;  // D row = node index
        Gp[(((m * 2 + kq) * 64 + fc * 16 + n16) * 4 + slot)] = pack2(acc0[r], acc1[r]);
      }
    }
    __syncthreads();
    // ---- phase 2: register-resident edge partials ----
#pragma unroll
    for (int s = 0; s < ESLOT; ++s) {
      const int li = w + 8 * s;
      if (li < ecnt && li < ECREG) {
        const int2 sd = eStage[li];
        const int m = sd.x - n0;
        const uint4* hp = (const uint4*)(hn1c + ((size_t)c * EE + e0 + li) * 8);
        uint4 hv0 = hp[0], hv1 = hp[1];
        const uint4* gb = (const uint4*)Gp + (size_t)(m * 2) * 64 + lane;
        uint4 g0 = gb[0], g1 = gb[64];
        float p = acc[s];
        p = dot2a(g0.x, hv0.x, p);
        p = dot2a(g0.y, hv0.y, p);
        p = dot2a(g0.z, hv0.z, p);
        p = dot2a(g0.w, hv0.w, p);
        p = dot2a(g1.x, hv1.x, p);
        p = dot2a(g1.y, hv1.y, p);
        p = dot2a(g1.z, hv1.z, p);
        p = dot2a(g1.w, hv1.w, p);
        acc[s] = p;
      }
    }
    // overflow edges (virtually never): per-chunk atomic path
    for (int li = ECREG + w; li < ecnt; li += 8) {
      const int ii = e0 + li;
      const int src = __builtin_amdgcn_readfirstlane(esd[2 * ii]);
      const int dst = __builtin_amdgcn_readfirstlane(esd[2 * ii + 1]);
      const int m = src - n0;
      float p = (half == 0 && cc == 0) ? nbias[(size_t)src * 64 + lane] : 0.f;
      const uint4* hp = (const uint4*)(hn1c + ((size_t)c * EE + ii) * 8);
      uint4 hv0 = hp[0], hv1 = hp[1];
      const uint4* gb = (const uint4*)Gp + (size_t)(m * 2) * 64 + lane;
      uint4 g0 = gb[0], g1 = gb[64];
      p = dot2a(g0.x, hv0.x, p);
      p = dot2a(g0.y, hv0.y, p);
      p = dot2a(g0.z, hv0.z, p);
      p = dot2a(g0.w, hv0.w, p);
      p = dot2a(g1.x, hv1.x, p);
      p = dot2a(g1.y, hv1.y, p);
      p = dot2a(g1.z, hv1.z, p);
      p = dot2a(g1.w, hv1.w, p);
      atomicAdd(&aggr[(size_t)dst * 64 + lane], p);
    }
  }
  // ---- commit: one atomic per register-tracked edge ----
#pragma unroll
  for (int s = 0; s < ESLOT; ++s) {
    const int li = w + 8 * s;
    if (li < ecnt && li < ECREG) {
      const int dst = eStage[li].y;
      atomicAdd(&aggr[(size_t)dst * 64 + lane], acc[s]);
    }
  }
}

// ---------------- h update: 4 nodes/block; residual + aggr + root GEMM; re-zeros aggr ----------------
__global__ __launch_bounds__(256) void k_update(
    float* __restrict__ h, uint_t* __restrict__ hpk,
    float* __restrict__ aggr, const float* __restrict__ bn2,
    const float* __restrict__ root, const float* __restrict__ cb,
    float* __restrict__ nbias, int l) {
  __shared__ float hl[4][DD];
  __shared__ float al[4][DD];
  const int tid = threadIdx.x, w = tid >> 6, f = tid & 63;
  const int n = blockIdx.x * 4 + w;
  float hv = h[(size_t)n * DD + f];
  hl[w][f] = hv;
  float acc = hv + aggr[(size_t)n * DD + f] + cb[l * DD + f];
  aggr[(size_t)n * DD + f] = 0.f;
  __syncthreads();
  const float* rp = root + (size_t)l * DD2;
#pragma unroll
  for (int d = 0; d < DD; ++d) acc += hl[w][d] * rp[d * DD + f];
  h[(size_t)n * DD + f] = acc;
  al[w][f] = acc;
  float other = __shfl_down(acc, 1);
  if ((f & 1) == 0)
    hpk[(size_t)n * 32 + (f >> 1)] = pack2(acc, other);
  __syncthreads();
  float nb = 0.f;
#pragma unroll
  for (int d = 0; d < DD; ++d) nb += al[w][d] * bn2[d * DD + f];
  nbias[(size_t)n * DD + f] = nb;
}

// ---------------- fused Set2Set (3x LSTM+attention) + output MLP ----------------
#define EVCAP 2048
__global__ void k_s2s(const float* __restrict__ h, const int* __restrict__ goff,
                      const float* __restrict__ Wiht, const float* __restrict__ Whht,
                      const float* __restrict__ lb,
                      const float* __restrict__ Wo1, const float* __restrict__ bo1,
                      const float* __restrict__ Wo2, const float* __restrict__ bo2,
                      void* __restrict__ outv, const int* __restrict__ flag) {
  __shared__ float qsl[K1];
  __shared__ float hsl[DD];
  __shared__ float csl[DD];
  __shared__ float gl[4][DD];
  __shared__ float red[256];
  __shared__ float ev[EVCAP];
  __shared__ float rp4[4][DD];
  const int g = blockIdx.x, tid = threadIdx.x;

  if (tid < K1) qsl[tid] = 0.f;
  else if (tid < K1 + DD) hsl[tid - K1] = 0.f;
  else csl[tid - K1 - DD] = 0.f;
  __syncthreads();

  const int i0 = goff[g];
  int cnt = goff[g + 1] - i0;
  if (cnt > EVCAP) cnt = EVCAP;

  for (int m = 0; m < MM; ++m) {
    {
      float a = lb[tid];
      for (int i = 0; i < K1; ++i) a += qsl[i] * Wiht[i * 256 + tid];
      for (int i = 0; i < DD; ++i) a += hsl[i] * Whht[i * 256 + tid];
      gl[tid >> 6][tid & 63] = a;
    }
    __syncthreads();
    if (tid < DD) {
      float ig = sigmf_(gl[0][tid]), fg = sigmf_(gl[1][tid]);
      float gg = tanhf(gl[2][tid]), og = sigmf_(gl[3][tid]);
      float c = fg * csl[tid] + ig * gg;
      csl[tid] = c;
      hsl[tid] = og * tanhf(c);
    }
    __syncthreads();
    float lmax = -1e30f;
    for (int jj = tid; jj < cnt; jj += 256) {
      const float* hp = h + (size_t)(i0 + jj) * DD;
      float e = 0.f;
#pragma unroll
      for (int d = 0; d < DD; ++d) e += hp[d] * hsl[d];
      ev[jj] = e;
      lmax = fmaxf(lmax, e);
    }
    red[tid] = lmax;
    __syncthreads();
    for (int s = 128; s > 0; s >>= 1) {
      if (tid < s) red[tid] = fmaxf(red[tid], red[tid + s]);
      __syncthreads();
    }
    const float emax = red[0];
    __syncthreads();
    float lsum = 0.f;
    for (int jj = tid; jj < cnt; jj += 256) {
      float ex = expf(ev[jj] - emax);
      ev[jj] = ex;
      lsum += ex;
    }
    red[tid] = lsum;
    __syncthreads();
    for (int s = 128; s > 0; s >>= 1) {
      if (tid < s) red[tid] += red[tid + s];
      __syncthreads();
    }
    const float denom = red[0];
    const int f = tid & 63, grp = tid >> 6;
    float acc = 0.f;
    for (int jj = grp; jj < cnt; jj += 4)
      acc += ev[jj] * h[(size_t)(i0 + jj) * DD + f];
    rp4[grp][f] = acc;
    __syncthreads();
    if (tid < DD) {
      float r = rp4[0][tid] + rp4[1][tid] + rp4[2][tid] + rp4[3][tid];
      r = (cnt > 0 && denom > 0.f) ? r / denom : 0.f;
      qsl[tid] = hsl[tid];
      qsl[DD + tid] = r;
    }
    __syncthreads();
  }
  if (tid < DD) {
    float t = bo1[tid];
    for (int i = 0; i < K1; ++i) t += qsl[i] * Wo1[i * DD + tid];
    float s = siluf_(t) * Wo2[tid];
    for (int off = 32; off > 0; off >>= 1) s += __shfl_down(s, off);
    if (tid == 0) {
      float v = s + bo2[0];
      if (*flag) ((ushort_t*)outv)[g] = f2bf(v);
      else       ((float*)outv)[g] = v;
    }
  }
}

extern "C" void kernel_launch(void* const* d_in, const int* in_sizes, int n_in,
                              void* d_out, int out_size, void* d_ws, size_t ws_size,
                              hipStream_t stream) {
  const void* x_r    = d_in[0];
  const int*  ei     = (const int*)d_in[1];
  const void* ea_r   = d_in[2];
  const int*  batch  = (const int*)d_in[3];
  const void* W0_r   = d_in[4];
  const void* b0_r   = d_in[5];
  const void* Wn1_r  = d_in[6];
  const void* bn1_r  = d_in[7];
  const void* Wn2_r  = d_in[8];
  const void* bn2_r  = d_in[9];
  const void* root_r = d_in[10];
  const void* cb_r   = d_in[11];
  const void* Wih_r  = d_in[12];
  const void* Whh_r  = d_in[13];
  const void* lb_r   = d_in[14];
  const void* Wo1_r  = d_in[15];
  const void* bo1_r  = d_in[16];
  const void* Wo2_r  = d_in[17];
  const void* bo2_r  = d_in[18];

  char* w = (char*)d_ws;
  size_t off = 0;
  auto alloc = [&](size_t bytes) -> void* {
    void* p = w + off;
    off = (off + bytes + 255) & ~(size_t)255;
    return p;
  };
  int* flag = (int*)alloc(4);
  float* xc    = (float*)alloc((size_t)NN * DIN_ * 4);
  float* eac   = (float*)alloc((size_t)EE * 4 * 4);
  float* W0c   = (float*)alloc((size_t)DIN_ * DD * 4);
  float* b0c   = (float*)alloc((size_t)DD * 4);
  float* Wn1c  = (float*)alloc((size_t)4 * K1 * 4);
  float* bn1c  = (float*)alloc((size_t)K1 * 4);
  float* bn2c  = (float*)alloc((size_t)DD2 * 4);
  float* rootc = (float*)alloc((size_t)LL * DD2 * 4);
  float* cbc   = (float*)alloc((size_t)LL * DD * 4);
  float* Wihc  = (float*)alloc((size_t)4 * DD * K1 * 4);
  float* Whhc  = (float*)alloc((size_t)4 * DD * DD * 4);
  float* lbc   = (float*)alloc((size_t)4 * DD * 4);
  float* Wo1c  = (float*)alloc((size_t)K1 * DD * 4);
  float* bo1c  = (float*)alloc((size_t)DD * 4);
  float* Wo2c  = (float*)alloc((size_t)DD * 4);
  float* bo2c  = (float*)alloc((size_t)4);
  float* Wiht  = (float*)alloc((size_t)K1 * 256 * 4);
  float* Whht  = (float*)alloc((size_t)DD * 256 * 4);
  uint_t* Wn2m = (uint_t*)alloc((size_t)64 * 4 * 2 * 2 * 64 * 4 * 4);  // 1 MB
  float*  h    = (float*)alloc((size_t)NN * DD * 4);
  uint_t* hpk  = (uint_t*)alloc((size_t)NN * 32 * 4);
  uint_t* hn1c = (uint_t*)alloc((size_t)EE * (K1 / 2) * 4);  // chunk-major
  float*  aggr = (float*)alloc((size_t)NN * DD * 4);
  float*  nbias= (float*)alloc((size_t)NN * DD * 4);
  int* cnts  = (int*)alloc((size_t)2 * NN * 4);
  int* rps   = (int*)alloc((size_t)(NN + 1) * 4);
  int* epos  = (int*)alloc((size_t)EE * 4);
  int* esd   = (int*)alloc((size_t)2 * EE * 4);
  int* goff  = (int*)alloc((size_t)(BB + 1) * 4);

  int* cnt_s = cnts;
  int* cur_s = cnts + NN;

  hipMemsetAsync(cnts, 0, (size_t)2 * NN * 4, stream);
  hipMemsetAsync(aggr, 0, (size_t)NN * DD * 4, stream);

  CanonArgs ca;
  const void* srcs[NCANON] = {x_r, ea_r, W0_r, b0_r, Wn1_r, bn1_r, bn2_r, root_r,
                              cb_r, Wih_r, Whh_r, lb_r, Wo1_r, bo1_r, Wo2_r, bo2_r};
  float* dsts[NCANON] = {xc, eac, W0c, b0c, Wn1c, bn1c, bn2c, rootc,
                         cbc, Wihc, Whhc, lbc, Wo1c, bo1c, Wo2c, bo2c};
  int cnts_c[NCANON] = {NN * DIN_, EE * 4, DIN_ * DD, DD, 4 * K1, K1, DD2, LL * DD2,
                        LL * DD, 4 * DD * K1, 4 * DD * DD, 4 * DD, K1 * DD, DD, DD, 1};
  for (int i = 0; i < NCANON; ++i) { ca.src[i] = srcs[i]; ca.dst[i] = dsts[i]; ca.n[i] = cnts_c[i]; }
  {
    dim3 grid((EE * 4 + 255) / 256, NCANON);
    k_canon<<<grid, 256, 0, stream>>>(ca, (const ushort_t*)ea_r, flag);
  }
  k_wn2m<<<K1, 256, 0, stream>>>(Wn2_r, Wn2m, flag);
  k_wT<<<(4 * DD * K1 + 255) / 256, 256, 0, stream>>>(Wihc, Whhc, Wiht, Whht);

  k_embed<<<NN, DD, 0, stream>>>(xc, W0c, b0c, bn2c, h, hpk, nbias);
  k_hist<<<(EE + 255) / 256, 256, 0, stream>>>(ei, cnt_s);
  k_scan<<<2, 1024, 0, stream>>>(cnt_s, rps, batch, goff);
  k_fill<<<(EE + 255) / 256, 256, 0, stream>>>(ei, rps, cur_s, epos, esd);
  k_edgemlp<<<(EE * (K1 / 2) + 255) / 256, 256, 0, stream>>>(eac, Wn1c, bn1c, epos, hn1c);

  for (int l = 0; l < LL; ++l) {
    k_conv<<<CSPL * (NN / NPB), 512, 0, stream>>>(hpk, hn1c, Wn2m, nbias, rps, esd, aggr);
    k_update<<<NN / 4, 256, 0, stream>>>(h, hpk, aggr, bn2c, rootc, cbc, nbias, l);
  }

  k_s2s<<<BB, 256, 0, stream>>>(h, goff, Wiht, Whht, lbc, Wo1c, bo1c, Wo2c, bo2c,
                                d_out, flag);
}